// Round 7
// baseline (444.897 us; speedup 1.0000x reference)
//
#include <hip/hip_runtime.h>
#include <hip/hip_bf16.h>

#define NROWS 8192
typedef unsigned short u16;
typedef short bf16x8 __attribute__((ext_vector_type(8)));
typedef float f32x4 __attribute__((ext_vector_type(4)));

__device__ __forceinline__ u16 f2b(float f) {   // fp32 -> bf16 RNE (finite data)
    unsigned u = __float_as_uint(f);
    unsigned r = (u + 0x7fffu + ((u >> 16) & 1u)) >> 16;
    return (u16)r;
}
__device__ __forceinline__ float b2f(u16 v) {
    return __uint_as_float(((unsigned)v) << 16);
}

template<int MODE> __device__ __forceinline__ float actf(float v) {
    if constexpr (MODE == 1) return fmaxf(v, 0.f);
    else if constexpr (MODE == 2) return v > 0.f ? v : 0.2f * v;
    else return v;
}

// ---------------------------------------------------------------------------
// Weight folds, parallelized. ws layout (floats):
//   WA[128*64]@0  bA[64]@8192  cA[64]@8256  WB[64*16]@8320  bB[16]@9344
//   cB[16]@9360  T2[64*32]@9376  v1[128]@11424  v2[32]@11552  T1[128*128]@16384
// ---------------------------------------------------------------------------
__global__ __launch_bounds__(256) void fold1(
    const float* __restrict__ W1, const float* __restrict__ b1,
    const float* __restrict__ Wg1,
    const float* __restrict__ W2, const float* __restrict__ b2,
    const float* __restrict__ Wg2, float* __restrict__ ws) {
    float* T2 = ws + 9376;
    float* v1 = ws + 11424;
    float* v2 = ws + 11552;
    float* T1 = ws + 16384;
    const int tid = threadIdx.x, b = blockIdx.x;
    if (b < 16) {                       // T1 = W1 @ Wg1
        int i = b * 8 + (tid >> 5), j4 = (tid & 31) << 2;
        float4 acc = {0, 0, 0, 0};
        for (int k = 0; k < 128; ++k) {
            float a = W1[i * 128 + k];
            float4 g = *(const float4*)&Wg1[k * 128 + j4];
            acc.x += a * g.x; acc.y += a * g.y; acc.z += a * g.z; acc.w += a * g.w;
        }
        *(float4*)&T1[i * 128 + j4] = acc;
    } else if (b == 16) {
        if (tid < 128) {
            float s = 0;
            for (int k = 0; k < 128; ++k) s += b1[k] * Wg1[k * 128 + tid];
            v1[tid] = s;
        } else if (tid < 160) {
            int j = tid - 128;
            float s = 0;
            for (int k = 0; k < 32; ++k) s += b2[k] * Wg2[k * 32 + j];
            v2[j] = s;
        }
    } else {                            // T2 = W2 @ Wg2
        for (int o4 = tid; o4 < 64 * 8; o4 += 256) {
            int i = o4 >> 3, j4 = (o4 & 7) << 2;
            float4 acc = {0, 0, 0, 0};
            for (int k = 0; k < 32; ++k) {
                float a = W2[i * 32 + k];
                float4 g = *(const float4*)&Wg2[k * 32 + j4];
                acc.x += a * g.x; acc.y += a * g.y; acc.z += a * g.z; acc.w += a * g.w;
            }
            *(float4*)&T2[i * 32 + j4] = acc;
        }
    }
}

__global__ __launch_bounds__(256) void fold2(
    const float* __restrict__ Wm1, const float* __restrict__ bm1,
    const float* __restrict__ bg1,
    const float* __restrict__ W3, const float* __restrict__ b3,
    const float* __restrict__ bg2, float* __restrict__ ws) {
    float* WA = ws + 0;
    float* bA = ws + 8192;
    float* cA = ws + 8256;
    float* WB = ws + 8320;
    float* bB = ws + 9344;
    float* cB = ws + 9360;
    const float* T2 = ws + 9376;
    const float* v1 = ws + 11424;
    const float* v2 = ws + 11552;
    const float* T1 = ws + 16384;
    const int tid = threadIdx.x, b = blockIdx.x;
    if (b < 8) {                        // WA = T1 @ Wm1
        int i = b * 16 + (tid >> 4), j4 = (tid & 15) << 2;
        float4 acc = {0, 0, 0, 0};
        for (int k = 0; k < 128; ++k) {
            float a = T1[i * 128 + k];
            float4 g = *(const float4*)&Wm1[k * 64 + j4];
            acc.x += a * g.x; acc.y += a * g.y; acc.z += a * g.z; acc.w += a * g.w;
        }
        *(float4*)&WA[i * 64 + j4] = acc;
    } else if (b == 8) {
        if (tid < 64) {
            float s = 0, c = 0;
            for (int k = 0; k < 128; ++k) {
                s += v1[k] * Wm1[k * 64 + tid];
                c += bg1[k] * Wm1[k * 64 + tid];
            }
            bA[tid] = s; cA[tid] = c + bm1[tid];
        } else if (tid < 80) {
            int j = tid - 64;
            float s = 0, c = 0;
            for (int k = 0; k < 32; ++k) {
                s += v2[k] * W3[k * 16 + j];
                c += bg2[k] * W3[k * 16 + j];
            }
            bB[j] = s; cB[j] = c + b3[j];
        }
    } else {                            // WB = T2 @ W3
        int i = tid >> 2, j4 = (tid & 3) << 2;
        float4 acc = {0, 0, 0, 0};
        for (int k = 0; k < 32; ++k) {
            float a = T2[i * 32 + k];
            float4 g = *(const float4*)&W3[k * 16 + j4];
            acc.x += a * g.x; acc.y += a * g.y; acc.z += a * g.z; acc.w += a * g.w;
        }
        *(float4*)&WB[i * 16 + j4] = acc;
    }
}

// ---------------------------------------------------------------------------
// Small row GEMM: out = AOUT( AIN(in)[N,K] @ W[K,M] + bias )
// OUTT=0: fp32 row-major [N,M].  OUTT=1: bf16 TRANSPOSED [M][NROWS] (S^T).
// ---------------------------------------------------------------------------
template<int K, int M, int AIN, int AOUT, int OUTT>
__global__ __launch_bounds__(256) void gemm_rows(
    const float* __restrict__ in, const float* __restrict__ W,
    const float* __restrict__ bias, void* __restrict__ outv) {
    constexpr int RB = 32;
    constexpr int TNs = (M >= 64) ? 4 : 2;
    constexpr int TXs = M / TNs;
    constexpr int TYs = 256 / TXs;
    constexpr int TMs = RB / TYs;
    static_assert(TMs >= 1 && TMs * TYs == RB, "bad cfg");
    __shared__ float in_t[K][RB + 4];
    __shared__ float w_s[K * M];
    __shared__ float bias_s[M];
    const int tid = threadIdx.x;
    const int b0 = blockIdx.x * RB;
    constexpr int K4 = K / 4;
    for (int g = tid; g < RB * K4; g += 256) {
        int r = g / K4, c4 = g % K4;
        float4 v = *(const float4*)&in[(size_t)(b0 + r) * K + c4 * 4];
        v.x = actf<AIN>(v.x); v.y = actf<AIN>(v.y);
        v.z = actf<AIN>(v.z); v.w = actf<AIN>(v.w);
        in_t[c4 * 4 + 0][r] = v.x;
        in_t[c4 * 4 + 1][r] = v.y;
        in_t[c4 * 4 + 2][r] = v.z;
        in_t[c4 * 4 + 3][r] = v.w;
    }
    for (int g = tid; g < K * M / 4; g += 256)
        ((float4*)w_s)[g] = ((const float4*)W)[g];
    if (tid < M) bias_s[tid] = bias ? bias[tid] : 0.f;
    __syncthreads();

    const int tx = tid % TXs, ty = tid / TXs;
    const int c0 = tx * TNs, r0 = ty * TMs;
    float acc[TMs][TNs] = {};
    for (int k = 0; k < K; ++k) {
        float a[TMs];
#pragma unroll
        for (int m = 0; m < TMs; ++m) a[m] = in_t[k][r0 + m];
        float w[TNs];
#pragma unroll
        for (int n = 0; n < TNs; ++n) w[n] = w_s[k * M + c0 + n];
#pragma unroll
        for (int m = 0; m < TMs; ++m)
#pragma unroll
            for (int n = 0; n < TNs; ++n) acc[m][n] += a[m] * w[n];
    }
#pragma unroll
    for (int m = 0; m < TMs; ++m) {
        float vres[TNs];
#pragma unroll
        for (int n = 0; n < TNs; ++n) vres[n] = actf<AOUT>(acc[m][n] + bias_s[c0 + n]);
        if constexpr (OUTT == 0) {
            float* op = &((float*)outv)[(size_t)(b0 + r0 + m) * M + c0];
            if constexpr (TNs == 4) { float4 o4 = {vres[0], vres[1], vres[2], vres[3]}; *(float4*)op = o4; }
            else                    { float2 o2 = {vres[0], vres[1]}; *(float2*)op = o2; }
        } else {
            u16* ot = (u16*)outv;
#pragma unroll
            for (int n = 0; n < TNs; ++n)
                ot[(size_t)(c0 + n) * NROWS + (b0 + r0 + m)] = f2b(vres[n]);
        }
    }
}

// ---------------------------------------------------------------------------
// Fused med chain, 16 rows/block, 512 blocks. Weights read from global
// (L1-resident, broadcast); only row panels live in LDS (~17KB -> 2 blk/CU).
// ---------------------------------------------------------------------------
template<int K, int M, int AOUT, int OMODE>  // OMODE 0: panel; 1: panel+global; 2: St only
__device__ __forceinline__ void layer_step(
    const float (*pin)[17], const float* __restrict__ w,
    const float* __restrict__ bias,
    float (*pout)[17], float* __restrict__ gout, u16* __restrict__ stout,
    int b0, int tid) {
    constexpr int TXs = M / 4;
    constexpr int TYs = 256 / TXs;
    constexpr int TMs = 16 / TYs;
    static_assert(TMs >= 1, "cfg");
    const int tx = tid % TXs, ty = tid / TXs;
    const int c0 = tx * 4, r0 = ty * TMs;
    float acc[TMs][4] = {};
    for (int k = 0; k < K; ++k) {
        float4 wv = *(const float4*)&w[k * M + c0];
#pragma unroll
        for (int m = 0; m < TMs; ++m) {
            float a = pin[k][r0 + m];
            acc[m][0] += a * wv.x; acc[m][1] += a * wv.y;
            acc[m][2] += a * wv.z; acc[m][3] += a * wv.w;
        }
    }
#pragma unroll
    for (int m = 0; m < TMs; ++m) {
        float v[4];
#pragma unroll
        for (int n = 0; n < 4; ++n) {
            float bv = bias ? bias[c0 + n] : 0.f;
            v[n] = actf<AOUT>(acc[m][n] + bv);
        }
        if constexpr (OMODE != 2) {
#pragma unroll
            for (int n = 0; n < 4; ++n) pout[c0 + n][r0 + m] = v[n];
        }
        if constexpr (OMODE == 1) {
            float4 o = {v[0], v[1], v[2], v[3]};
            *(float4*)&gout[(size_t)(b0 + r0 + m) * M + c0] = o;
        }
        if constexpr (OMODE == 2) {
#pragma unroll
            for (int n = 0; n < 4; ++n)
                stout[(size_t)(c0 + n) * NROWS + (b0 + r0 + m)] = f2b(v[n]);
        }
    }
}

__global__ __launch_bounds__(256) void med_chain(
    const float* __restrict__ gA,
    const float* __restrict__ Wm2, const float* __restrict__ bm2,
    const float* __restrict__ Wm3, const float* __restrict__ bm3,
    const float* __restrict__ Wm4, const float* __restrict__ bm4,
    const float* __restrict__ Wgh,
    float* __restrict__ h4, u16* __restrict__ St) {
    __shared__ __align__(16) float P0[64][17];
    __shared__ __align__(16) float P1[128][17];
    __shared__ __align__(16) float P2[64][17];
    const int tid = threadIdx.x;
    const int b0 = blockIdx.x * 16;

    // load input panel (16 rows x 64 cols), apply lrelu
    {
        int r = tid >> 4, c4 = tid & 15;
        float4 v = *(const float4*)&gA[(size_t)(b0 + r) * 64 + c4 * 4];
        P0[c4 * 4 + 0][r] = actf<2>(v.x);
        P0[c4 * 4 + 1][r] = actf<2>(v.y);
        P0[c4 * 4 + 2][r] = actf<2>(v.z);
        P0[c4 * 4 + 3][r] = actf<2>(v.w);
    }
    __syncthreads();
    layer_step<64, 128, 2, 0>(P0, Wm2, bm2, P1, nullptr, nullptr, b0, tid);
    __syncthreads();
    layer_step<128, 64, 2, 0>(P1, Wm3, bm3, P2, nullptr, nullptr, b0, tid);
    __syncthreads();
    layer_step<64, 64, 1, 1>(P2, Wm4, bm4, P0, h4, nullptr, b0, tid);
    __syncthreads();
    layer_step<64, 64, 0, 2>(P0, Wgh, nullptr, nullptr, nullptr, St, b0, tid);
}

// ---------------------------------------------------------------------------
// MFMA aggregation: P[ky] = bf16( A[rows, kchunk] @ S )  (no LDS, no atomics)
// wave: 16 rows x F cols; A-frag/B-frag = direct 16B global loads.
// MODE 0: A from Abf.  MODE 1: A = bf16(adj*dis) on the fly (NT reads) + write
// Abf.  MODE 2: on the fly, no write.  KS=16 -> 2048 blocks -> ~8 blk/CU TLP.
// ---------------------------------------------------------------------------
template<int F, int MODE, int KS>
__global__ __launch_bounds__(256) void agg_mfma(
    u16* __restrict__ Abf, const float* __restrict__ adj,
    const float* __restrict__ dis, const u16* __restrict__ St,
    u16* __restrict__ Pout) {
    constexpr int CT = F / 16;
    constexpr int KCH = NROWS / KS;
    const int lane = threadIdx.x & 63;
    const int wid  = threadIdx.x >> 6;
    const int r0   = blockIdx.x * 64 + wid * 16;
    const int ky   = blockIdx.y;
    const int l15  = lane & 15;
    const int kb   = (lane >> 4) * 8;
    const int k0   = ky * KCH;
    f32x4 acc[CT] = {};
    size_t aoff = (size_t)(r0 + l15) * NROWS + k0 + kb;
    const u16* Bbase = St + (size_t)l15 * NROWS + k0 + kb;
#pragma unroll 4
    for (int ks = 0; ks < KCH; ks += 32) {
        bf16x8 af;
        if constexpr (MODE == 0) {
            af = *(const bf16x8*)(Abf + aoff);
        } else {
            const f32x4* a4 = (const f32x4*)(adj + aoff);
            const f32x4* d4 = (const f32x4*)(dis + aoff);
            f32x4 a0 = __builtin_nontemporal_load(a4);
            f32x4 a1 = __builtin_nontemporal_load(a4 + 1);
            f32x4 d0 = __builtin_nontemporal_load(d4);
            f32x4 d1 = __builtin_nontemporal_load(d4 + 1);
#pragma unroll
            for (int j = 0; j < 4; ++j) {
                af[j]     = (short)f2b(a0[j] * d0[j]);
                af[j + 4] = (short)f2b(a1[j] * d1[j]);
            }
            if constexpr (MODE == 1)
                *(bf16x8*)(Abf + aoff) = af;   // normal store -> stays in L2/L3
        }
#pragma unroll
        for (int ct = 0; ct < CT; ++ct) {
            bf16x8 bf = *(const bf16x8*)(Bbase + (size_t)ct * 16 * NROWS + ks);
            acc[ct] = __builtin_amdgcn_mfma_f32_16x16x32_bf16(af, bf, acc[ct], 0, 0, 0);
        }
        aoff += 32;
    }
    // C/D layout: col = lane&15, row = (lane>>4)*4 + i   [m89-verified]
    u16* P = Pout + (size_t)ky * ((size_t)NROWS * F);
    const int rb = r0 + (lane >> 4) * 4;
#pragma unroll
    for (int ct = 0; ct < CT; ++ct)
#pragma unroll
        for (int i = 0; i < 4; ++i)
            P[(size_t)(rb + i) * F + ct * 16 + l15] = f2b(acc[ct][i]);
}

// ---------------------------------------------------------------------------
// out = sum_{ky} b2f(P[ky]) + bias[col] (+ res)   (thread = 8 consecutive)
// ---------------------------------------------------------------------------
template<int F, int KS>
__global__ __launch_bounds__(256) void reduce_add(
    const u16* __restrict__ P, const float* __restrict__ bias,
    const float* __restrict__ res, float* __restrict__ out) {
    constexpr int TOT8 = NROWS * F / 8;
    int i8 = blockIdx.x * 256 + threadIdx.x;
    if (i8 >= TOT8) return;
    constexpr size_t STR = (size_t)NROWS * F;
    float s[8] = {};
#pragma unroll
    for (int k = 0; k < KS; ++k) {
        bf16x8 v = *(const bf16x8*)(P + (size_t)k * STR + (size_t)i8 * 8);
#pragma unroll
        for (int j = 0; j < 8; ++j) s[j] += b2f((u16)v[j]);
    }
    const int c0 = (i8 * 8) % F;
#pragma unroll
    for (int j = 0; j < 8; ++j) s[j] += bias[c0 + j];
    if (res) {
        const float4* r4 = (const float4*)(res + (size_t)i8 * 8);
        float4 ra = r4[0], rb = r4[1];
        s[0] += ra.x; s[1] += ra.y; s[2] += ra.z; s[3] += ra.w;
        s[4] += rb.x; s[5] += rb.y; s[6] += rb.z; s[7] += rb.w;
    }
    float4* o4 = (float4*)(out + (size_t)i8 * 8);
    float4 oa = {s[0], s[1], s[2], s[3]}, ob = {s[4], s[5], s[6], s[7]};
    o4[0] = oa; o4[1] = ob;
}

extern "C" void kernel_launch(void* const* d_in, const int* in_sizes, int n_in,
                              void* d_out, int out_size, void* d_ws, size_t ws_size,
                              hipStream_t stream) {
    const float* x   = (const float*)d_in[0];
    const float* adj = (const float*)d_in[1];
    const float* dis = (const float*)d_in[2];
    const float* W1  = (const float*)d_in[3];
    const float* b1  = (const float*)d_in[4];
    const float* Wg1 = (const float*)d_in[5];
    const float* bg1 = (const float*)d_in[6];
    const float* Wm1 = (const float*)d_in[7];
    const float* bm1 = (const float*)d_in[8];
    const float* Wm2 = (const float*)d_in[9];
    const float* bm2 = (const float*)d_in[10];
    const float* Wm3 = (const float*)d_in[11];
    const float* bm3 = (const float*)d_in[12];
    const float* Wm4 = (const float*)d_in[13];
    const float* bm4 = (const float*)d_in[14];
    const float* Wgh = (const float*)d_in[15];
    const float* bgh = (const float*)d_in[16];
    const float* W2  = (const float*)d_in[17];
    const float* b2  = (const float*)d_in[18];
    const float* Wg2 = (const float*)d_in[19];
    const float* bg2 = (const float*)d_in[20];
    const float* W3  = (const float*)d_in[21];
    const float* b3  = (const float*)d_in[22];
    float* ws  = (float*)d_ws;
    float* out = (float*)d_out;

    constexpr int KS = 16;
    const size_t ABF_FLOATS = (size_t)NROWS * NROWS / 2;   // 128MB as floats
    // P is bf16: KS * 8192*64 u16 = 4,194,304 float-equivalents
    const size_t P_FLOATS = (size_t)KS * NROWS * 64 / 2;
    const size_t BASE_FLOATS = 40960 + 262144 + P_FLOATS + 524288 + 524288;
    const size_t NEED_PRE_BYTES = (ABF_FLOATS + BASE_FLOATS) * 4ULL;  // ~156.4MB (known good)
    const bool pre = ws_size >= NEED_PRE_BYTES;

    float* base = ws + (pre ? ABF_FLOATS : 0);
    float* wsW  = base;                       // fold area: 40960 floats
    float* St_f = wsW + 40960;                // S^T bf16 [64][8192] (shared)
    float* P_f  = St_f + 262144;              // partials bf16: KS*8192*64
    float* gA   = P_f + P_FLOATS;             // [8192,64]
    float* h4   = gA + 524288;                // [8192,64]
    float* g2   = gA;                         // alias: gA dead after med_chain

    u16* Abf = (u16*)ws;
    u16* St  = (u16*)St_f;
    u16* P   = (u16*)P_f;
    const float* WA = wsW + 0;
    const float* bA = wsW + 8192;
    const float* cA = wsW + 8256;
    const float* WB = wsW + 8320;
    const float* bB = wsW + 9344;
    const float* cB = wsW + 9360;

    fold1<<<18, 256, 0, stream>>>(W1, b1, Wg1, W2, b2, Wg2, wsW);
    fold2<<<10, 256, 0, stream>>>(Wm1, bm1, bg1, W3, b3, bg2, wsW);

    // pass 1 (fused converter): sA^T = (x @ WA + bA)^T ; gA = A@sA + cA
    gemm_rows<128, 64, 0, 0, 1><<<256, 256, 0, stream>>>(x, WA, bA, St);
    if (pre) agg_mfma<64, 1, KS><<<dim3(128, KS), 256, 0, stream>>>(Abf, adj, dis, St, P);
    else     agg_mfma<64, 2, KS><<<dim3(128, KS), 256, 0, stream>>>(nullptr, adj, dis, St, P);
    reduce_add<64, KS><<<256, 256, 0, stream>>>(P, cA, nullptr, gA);

    // fused med chain: gA -> h4 (global) + s2^T (St, bf16)
    med_chain<<<512, 256, 0, stream>>>(gA, Wm2, bm2, Wm3, bm3, Wm4, bm4, Wgh, h4, St);

    // pass 2: g2 = A@s2 + bgh + h4
    if (pre) agg_mfma<64, 0, KS><<<dim3(128, KS), 256, 0, stream>>>(Abf, nullptr, nullptr, St, P);
    else     agg_mfma<64, 2, KS><<<dim3(128, KS), 256, 0, stream>>>(nullptr, adj, dis, St, P);
    reduce_add<64, KS><<<256, 256, 0, stream>>>(P, bgh, h4, g2);

    // pass 3: sB^T = (relu(g2) @ WB + bB)^T ; out = A@sB + cB
    gemm_rows<64, 16, 1, 0, 1><<<256, 256, 0, stream>>>(g2, WB, bB, St);
    if (pre) agg_mfma<16, 0, KS><<<dim3(128, KS), 256, 0, stream>>>(Abf, nullptr, nullptr, St, P);
    else     agg_mfma<16, 2, KS><<<dim3(128, KS), 256, 0, stream>>>(nullptr, adj, dis, St, P);
    reduce_add<16, KS><<<64, 256, 0, stream>>>(P, cB, nullptr, out);
}

// Round 8
// 326.024 us; speedup vs baseline: 1.3646x; 1.3646x over previous
//
#include <hip/hip_runtime.h>
#include <hip/hip_bf16.h>

#define NROWS 8192
typedef unsigned short u16;
typedef short bf16x8 __attribute__((ext_vector_type(8)));
typedef short bf16x4 __attribute__((ext_vector_type(4)));
typedef float f32x4 __attribute__((ext_vector_type(4)));

__device__ __forceinline__ u16 f2b(float f) {   // fp32 -> bf16 RNE (finite data)
    unsigned u = __float_as_uint(f);
    unsigned r = (u + 0x7fffu + ((u >> 16) & 1u)) >> 16;
    return (u16)r;
}
__device__ __forceinline__ float b2f(u16 v) {
    return __uint_as_float(((unsigned)v) << 16);
}

template<int MODE> __device__ __forceinline__ float actf(float v) {
    if constexpr (MODE == 1) return fmaxf(v, 0.f);
    else if constexpr (MODE == 2) return v > 0.f ? v : 0.2f * v;
    else return v;
}

// ---------------------------------------------------------------------------
// Weight folds, parallelized. ws layout (floats):
//   WA[128*64]@0  bA[64]@8192  cA[64]@8256  WB[64*16]@8320  bB[16]@9344
//   cB[16]@9360  T2[64*32]@9376  v1[128]@11424  v2[32]@11552  T1[128*128]@16384
// ---------------------------------------------------------------------------
__global__ __launch_bounds__(256) void fold1(
    const float* __restrict__ W1, const float* __restrict__ b1,
    const float* __restrict__ Wg1,
    const float* __restrict__ W2, const float* __restrict__ b2,
    const float* __restrict__ Wg2, float* __restrict__ ws) {
    float* T2 = ws + 9376;
    float* v1 = ws + 11424;
    float* v2 = ws + 11552;
    float* T1 = ws + 16384;
    const int tid = threadIdx.x, b = blockIdx.x;
    if (b < 16) {                       // T1 = W1 @ Wg1
        int i = b * 8 + (tid >> 5), j4 = (tid & 31) << 2;
        float4 acc = {0, 0, 0, 0};
        for (int k = 0; k < 128; ++k) {
            float a = W1[i * 128 + k];
            float4 g = *(const float4*)&Wg1[k * 128 + j4];
            acc.x += a * g.x; acc.y += a * g.y; acc.z += a * g.z; acc.w += a * g.w;
        }
        *(float4*)&T1[i * 128 + j4] = acc;
    } else if (b == 16) {
        if (tid < 128) {
            float s = 0;
            for (int k = 0; k < 128; ++k) s += b1[k] * Wg1[k * 128 + tid];
            v1[tid] = s;
        } else if (tid < 160) {
            int j = tid - 128;
            float s = 0;
            for (int k = 0; k < 32; ++k) s += b2[k] * Wg2[k * 32 + j];
            v2[j] = s;
        }
    } else {                            // T2 = W2 @ Wg2
        for (int o4 = tid; o4 < 64 * 8; o4 += 256) {
            int i = o4 >> 3, j4 = (o4 & 7) << 2;
            float4 acc = {0, 0, 0, 0};
            for (int k = 0; k < 32; ++k) {
                float a = W2[i * 32 + k];
                float4 g = *(const float4*)&Wg2[k * 32 + j4];
                acc.x += a * g.x; acc.y += a * g.y; acc.z += a * g.z; acc.w += a * g.w;
            }
            *(float4*)&T2[i * 32 + j4] = acc;
        }
    }
}

__global__ __launch_bounds__(256) void fold2(
    const float* __restrict__ Wm1, const float* __restrict__ bm1,
    const float* __restrict__ bg1,
    const float* __restrict__ W3, const float* __restrict__ b3,
    const float* __restrict__ bg2, float* __restrict__ ws) {
    float* WA = ws + 0;
    float* bA = ws + 8192;
    float* cA = ws + 8256;
    float* WB = ws + 8320;
    float* bB = ws + 9344;
    float* cB = ws + 9360;
    const float* T2 = ws + 9376;
    const float* v1 = ws + 11424;
    const float* v2 = ws + 11552;
    const float* T1 = ws + 16384;
    const int tid = threadIdx.x, b = blockIdx.x;
    if (b < 8) {                        // WA = T1 @ Wm1
        int i = b * 16 + (tid >> 4), j4 = (tid & 15) << 2;
        float4 acc = {0, 0, 0, 0};
        for (int k = 0; k < 128; ++k) {
            float a = T1[i * 128 + k];
            float4 g = *(const float4*)&Wm1[k * 64 + j4];
            acc.x += a * g.x; acc.y += a * g.y; acc.z += a * g.z; acc.w += a * g.w;
        }
        *(float4*)&WA[i * 64 + j4] = acc;
    } else if (b == 8) {
        if (tid < 64) {
            float s = 0, c = 0;
            for (int k = 0; k < 128; ++k) {
                s += v1[k] * Wm1[k * 64 + tid];
                c += bg1[k] * Wm1[k * 64 + tid];
            }
            bA[tid] = s; cA[tid] = c + bm1[tid];
        } else if (tid < 80) {
            int j = tid - 64;
            float s = 0, c = 0;
            for (int k = 0; k < 32; ++k) {
                s += v2[k] * W3[k * 16 + j];
                c += bg2[k] * W3[k * 16 + j];
            }
            bB[j] = s; cB[j] = c + b3[j];
        }
    } else {                            // WB = T2 @ W3
        int i = tid >> 2, j4 = (tid & 3) << 2;
        float4 acc = {0, 0, 0, 0};
        for (int k = 0; k < 32; ++k) {
            float a = T2[i * 32 + k];
            float4 g = *(const float4*)&W3[k * 16 + j4];
            acc.x += a * g.x; acc.y += a * g.y; acc.z += a * g.z; acc.w += a * g.w;
        }
        *(float4*)&WB[i * 16 + j4] = acc;
    }
}

// ---------------------------------------------------------------------------
// Small row GEMM: out = AOUT( AIN(in)[N,K] @ W[K,M] + bias )
// OUTT=0: fp32 row-major [N,M].  OUTT=1: bf16 TRANSPOSED [M][NROWS] (S^T).
// ---------------------------------------------------------------------------
template<int K, int M, int AIN, int AOUT, int OUTT>
__global__ __launch_bounds__(256) void gemm_rows(
    const float* __restrict__ in, const float* __restrict__ W,
    const float* __restrict__ bias, void* __restrict__ outv) {
    constexpr int RB = 32;
    constexpr int TNs = (M >= 64) ? 4 : 2;
    constexpr int TXs = M / TNs;
    constexpr int TYs = 256 / TXs;
    constexpr int TMs = RB / TYs;
    static_assert(TMs >= 1 && TMs * TYs == RB, "bad cfg");
    __shared__ float in_t[K][RB + 4];
    __shared__ float w_s[K * M];
    __shared__ float bias_s[M];
    const int tid = threadIdx.x;
    const int b0 = blockIdx.x * RB;
    constexpr int K4 = K / 4;
    for (int g = tid; g < RB * K4; g += 256) {
        int r = g / K4, c4 = g % K4;
        float4 v = *(const float4*)&in[(size_t)(b0 + r) * K + c4 * 4];
        v.x = actf<AIN>(v.x); v.y = actf<AIN>(v.y);
        v.z = actf<AIN>(v.z); v.w = actf<AIN>(v.w);
        in_t[c4 * 4 + 0][r] = v.x;
        in_t[c4 * 4 + 1][r] = v.y;
        in_t[c4 * 4 + 2][r] = v.z;
        in_t[c4 * 4 + 3][r] = v.w;
    }
    for (int g = tid; g < K * M / 4; g += 256)
        ((float4*)w_s)[g] = ((const float4*)W)[g];
    if (tid < M) bias_s[tid] = bias ? bias[tid] : 0.f;
    __syncthreads();

    const int tx = tid % TXs, ty = tid / TXs;
    const int c0 = tx * TNs, r0 = ty * TMs;
    float acc[TMs][TNs] = {};
    for (int k = 0; k < K; ++k) {
        float a[TMs];
#pragma unroll
        for (int m = 0; m < TMs; ++m) a[m] = in_t[k][r0 + m];
        float w[TNs];
#pragma unroll
        for (int n = 0; n < TNs; ++n) w[n] = w_s[k * M + c0 + n];
#pragma unroll
        for (int m = 0; m < TMs; ++m)
#pragma unroll
            for (int n = 0; n < TNs; ++n) acc[m][n] += a[m] * w[n];
    }
#pragma unroll
    for (int m = 0; m < TMs; ++m) {
        float vres[TNs];
#pragma unroll
        for (int n = 0; n < TNs; ++n) vres[n] = actf<AOUT>(acc[m][n] + bias_s[c0 + n]);
        if constexpr (OUTT == 0) {
            float* op = &((float*)outv)[(size_t)(b0 + r0 + m) * M + c0];
            if constexpr (TNs == 4) { float4 o4 = {vres[0], vres[1], vres[2], vres[3]}; *(float4*)op = o4; }
            else                    { float2 o2 = {vres[0], vres[1]}; *(float2*)op = o2; }
        } else {
            u16* ot = (u16*)outv;
#pragma unroll
            for (int n = 0; n < TNs; ++n)
                ot[(size_t)(c0 + n) * NROWS + (b0 + r0 + m)] = f2b(vres[n]);
        }
    }
}

// ---------------------------------------------------------------------------
// Fused med chain, 16 rows/block, 512 blocks. Weights read from global
// (L1-resident broadcast); row panels in LDS (~17KB).
// ---------------------------------------------------------------------------
template<int K, int M, int AOUT, int OMODE>  // OMODE 0: panel; 1: panel+global; 2: St only
__device__ __forceinline__ void layer_step(
    const float (*pin)[17], const float* __restrict__ w,
    const float* __restrict__ bias,
    float (*pout)[17], float* __restrict__ gout, u16* __restrict__ stout,
    int b0, int tid) {
    constexpr int TXs = M / 4;
    constexpr int TYs = 256 / TXs;
    constexpr int TMs = 16 / TYs;
    static_assert(TMs >= 1, "cfg");
    const int tx = tid % TXs, ty = tid / TXs;
    const int c0 = tx * 4, r0 = ty * TMs;
    float acc[TMs][4] = {};
    for (int k = 0; k < K; ++k) {
        float4 wv = *(const float4*)&w[k * M + c0];
#pragma unroll
        for (int m = 0; m < TMs; ++m) {
            float a = pin[k][r0 + m];
            acc[m][0] += a * wv.x; acc[m][1] += a * wv.y;
            acc[m][2] += a * wv.z; acc[m][3] += a * wv.w;
        }
    }
#pragma unroll
    for (int m = 0; m < TMs; ++m) {
        float v[4];
#pragma unroll
        for (int n = 0; n < 4; ++n) {
            float bv = bias ? bias[c0 + n] : 0.f;
            v[n] = actf<AOUT>(acc[m][n] + bv);
        }
        if constexpr (OMODE != 2) {
#pragma unroll
            for (int n = 0; n < 4; ++n) pout[c0 + n][r0 + m] = v[n];
        }
        if constexpr (OMODE == 1) {
            float4 o = {v[0], v[1], v[2], v[3]};
            *(float4*)&gout[(size_t)(b0 + r0 + m) * M + c0] = o;
        }
        if constexpr (OMODE == 2) {
#pragma unroll
            for (int n = 0; n < 4; ++n)
                stout[(size_t)(c0 + n) * NROWS + (b0 + r0 + m)] = f2b(v[n]);
        }
    }
}

__global__ __launch_bounds__(256) void med_chain(
    const float* __restrict__ gA,
    const float* __restrict__ Wm2, const float* __restrict__ bm2,
    const float* __restrict__ Wm3, const float* __restrict__ bm3,
    const float* __restrict__ Wm4, const float* __restrict__ bm4,
    const float* __restrict__ Wgh,
    float* __restrict__ h4, u16* __restrict__ St) {
    __shared__ __align__(16) float P0[64][17];
    __shared__ __align__(16) float P1[128][17];
    __shared__ __align__(16) float P2[64][17];
    const int tid = threadIdx.x;
    const int b0 = blockIdx.x * 16;

    {
        int r = tid >> 4, c4 = tid & 15;
        float4 v = *(const float4*)&gA[(size_t)(b0 + r) * 64 + c4 * 4];
        P0[c4 * 4 + 0][r] = actf<2>(v.x);
        P0[c4 * 4 + 1][r] = actf<2>(v.y);
        P0[c4 * 4 + 2][r] = actf<2>(v.z);
        P0[c4 * 4 + 3][r] = actf<2>(v.w);
    }
    __syncthreads();
    layer_step<64, 128, 2, 0>(P0, Wm2, bm2, P1, nullptr, nullptr, b0, tid);
    __syncthreads();
    layer_step<128, 64, 2, 0>(P1, Wm3, bm3, P2, nullptr, nullptr, b0, tid);
    __syncthreads();
    layer_step<64, 64, 1, 1>(P2, Wm4, bm4, P0, h4, nullptr, b0, tid);
    __syncthreads();
    layer_step<64, 64, 0, 2>(P0, Wgh, nullptr, nullptr, nullptr, St, b0, tid);
}

// ---------------------------------------------------------------------------
// LDS-staged MFMA aggregation: P[ky] = bf16( A[64 rows, KCH] @ S )
// Coalesced global loads -> XOR-swizzled LDS tiles -> ds_read_b128 fragments.
// MODE 0: A from Abf (bf16, L3-warm).  MODE 1: A = bf16(adj*dis) on the fly
// (NT fp32 reads) + write Abf.  MODE 2: on the fly, no Abf write.
// Swizzle (G4): byte ^= ((row&7)<<4) on both LDS write and read; fragment
// reads (16 lanes, 16 rows, same k) become <=2-way (free, m136).
// ---------------------------------------------------------------------------
template<int F, int MODE, int KS>
__global__ __launch_bounds__(256) void agg_mfma(
    u16* __restrict__ Abf, const float* __restrict__ adj,
    const float* __restrict__ dis, const u16* __restrict__ St,
    u16* __restrict__ Pout) {
    constexpr int CT = F / 16;
    constexpr int BK = 128;
    constexpr int KCH = NROWS / KS;
    constexpr int NCH = KCH / BK;
    __shared__ __align__(16) u16 As[64 * BK];   // 16KB
    __shared__ __align__(16) u16 Bs[F * BK];    // 16KB (F=64) / 4KB (F=16)
    const int tid  = threadIdx.x;
    const int lane = tid & 63;
    const int wid  = tid >> 6;
    const int i0   = blockIdx.x * 64;
    const int ky   = blockIdx.y;
    const int l15  = lane & 15;
    const int kb   = (lane >> 4) * 8;
    const int k0   = ky * KCH;
    f32x4 acc[CT] = {};

    for (int ch = 0; ch < NCH; ++ch) {
        const int kc = k0 + ch * BK;
        // ---- stage A tile (64 x BK), coalesced ----
        if constexpr (MODE == 0) {
#pragma unroll
            for (int r = 0; r < (64 * BK) / (256 * 8); ++r) {
                int e8  = r * 256 + tid;
                int row = e8 >> 4;             // 16 x 8-elem groups per row
                int col = (e8 & 15) * 8;
                bf16x8 v = *(const bf16x8*)(Abf + (size_t)(i0 + row) * NROWS + kc + col);
                int bo = ((row * BK + col) * 2) ^ ((row & 7) << 4);
                *(bf16x8*)((char*)As + bo) = v;
            }
        } else {
#pragma unroll
            for (int r = 0; r < (64 * BK) / (256 * 4); ++r) {
                int e4  = r * 256 + tid;
                int row = e4 >> 5;             // 32 x 4-elem groups per row
                int col = (e4 & 31) * 4;
                size_t g = (size_t)(i0 + row) * NROWS + kc + col;
                f32x4 a = __builtin_nontemporal_load((const f32x4*)(adj + g));
                f32x4 d = __builtin_nontemporal_load((const f32x4*)(dis + g));
                bf16x4 v;
#pragma unroll
                for (int j = 0; j < 4; ++j) v[j] = (short)f2b(a[j] * d[j]);
                if constexpr (MODE == 1) *(bf16x4*)(Abf + g) = v;
                int bo = ((row * BK + col) * 2) ^ ((row & 7) << 4);
                *(bf16x4*)((char*)As + bo) = v;
            }
        }
        // ---- stage B tile (F x BK) from St, coalesced; reused by all 4 waves ----
#pragma unroll
        for (int r = 0; r < (F * BK) / (256 * 8); ++r) {
            int e8  = r * 256 + tid;
            int c   = e8 >> 4;
            int col = (e8 & 15) * 8;
            bf16x8 v = *(const bf16x8*)(St + (size_t)c * NROWS + kc + col);
            int bo = ((c * BK + col) * 2) ^ ((c & 7) << 4);
            *(bf16x8*)((char*)Bs + bo) = v;
        }
        __syncthreads();
        // ---- compute: BK/32 MFMA k-steps ----
#pragma unroll
        for (int ks = 0; ks < BK; ks += 32) {
            const int arow = wid * 16 + l15;
            int ao = ((arow * BK + ks + kb) * 2) ^ ((arow & 7) << 4);
            bf16x8 af = *(const bf16x8*)((const char*)As + ao);
#pragma unroll
            for (int ct = 0; ct < CT; ++ct) {
                int bcol = ct * 16 + l15;
                int bo = ((bcol * BK + ks + kb) * 2) ^ ((bcol & 7) << 4);
                bf16x8 bf = *(const bf16x8*)((const char*)Bs + bo);
                acc[ct] = __builtin_amdgcn_mfma_f32_16x16x32_bf16(af, bf, acc[ct], 0, 0, 0);
            }
        }
        __syncthreads();
    }
    // C/D layout: col = lane&15, row = (lane>>4)*4 + i   [m89-verified]
    u16* P = Pout + (size_t)ky * ((size_t)NROWS * F);
    const int rb = i0 + wid * 16 + (lane >> 4) * 4;
#pragma unroll
    for (int ct = 0; ct < CT; ++ct)
#pragma unroll
        for (int i = 0; i < 4; ++i)
            P[(size_t)(rb + i) * F + ct * 16 + l15] = f2b(acc[ct][i]);
}

// ---------------------------------------------------------------------------
// out = sum_{ky} b2f(P[ky]) + bias[col] (+ res)   (thread = 8 consecutive)
// ---------------------------------------------------------------------------
template<int F, int KS>
__global__ __launch_bounds__(256) void reduce_add(
    const u16* __restrict__ P, const float* __restrict__ bias,
    const float* __restrict__ res, float* __restrict__ out) {
    constexpr int TOT8 = NROWS * F / 8;
    int i8 = blockIdx.x * 256 + threadIdx.x;
    if (i8 >= TOT8) return;
    constexpr size_t STR = (size_t)NROWS * F;
    float s[8] = {};
#pragma unroll
    for (int k = 0; k < KS; ++k) {
        bf16x8 v = *(const bf16x8*)(P + (size_t)k * STR + (size_t)i8 * 8);
#pragma unroll
        for (int j = 0; j < 8; ++j) s[j] += b2f((u16)v[j]);
    }
    const int c0 = (i8 * 8) % F;
#pragma unroll
    for (int j = 0; j < 8; ++j) s[j] += bias[c0 + j];
    if (res) {
        const float4* r4 = (const float4*)(res + (size_t)i8 * 8);
        float4 ra = r4[0], rb = r4[1];
        s[0] += ra.x; s[1] += ra.y; s[2] += ra.z; s[3] += ra.w;
        s[4] += rb.x; s[5] += rb.y; s[6] += rb.z; s[7] += rb.w;
    }
    float4* o4 = (float4*)(out + (size_t)i8 * 8);
    float4 oa = {s[0], s[1], s[2], s[3]}, ob = {s[4], s[5], s[6], s[7]};
    o4[0] = oa; o4[1] = ob;
}

extern "C" void kernel_launch(void* const* d_in, const int* in_sizes, int n_in,
                              void* d_out, int out_size, void* d_ws, size_t ws_size,
                              hipStream_t stream) {
    const float* x   = (const float*)d_in[0];
    const float* adj = (const float*)d_in[1];
    const float* dis = (const float*)d_in[2];
    const float* W1  = (const float*)d_in[3];
    const float* b1  = (const float*)d_in[4];
    const float* Wg1 = (const float*)d_in[5];
    const float* bg1 = (const float*)d_in[6];
    const float* Wm1 = (const float*)d_in[7];
    const float* bm1 = (const float*)d_in[8];
    const float* Wm2 = (const float*)d_in[9];
    const float* bm2 = (const float*)d_in[10];
    const float* Wm3 = (const float*)d_in[11];
    const float* bm3 = (const float*)d_in[12];
    const float* Wm4 = (const float*)d_in[13];
    const float* bm4 = (const float*)d_in[14];
    const float* Wgh = (const float*)d_in[15];
    const float* bgh = (const float*)d_in[16];
    const float* W2  = (const float*)d_in[17];
    const float* b2  = (const float*)d_in[18];
    const float* Wg2 = (const float*)d_in[19];
    const float* bg2 = (const float*)d_in[20];
    const float* W3  = (const float*)d_in[21];
    const float* b3  = (const float*)d_in[22];
    float* ws  = (float*)d_ws;
    float* out = (float*)d_out;

    constexpr int KS = 16;
    const size_t ABF_FLOATS = (size_t)NROWS * NROWS / 2;   // 128MB as floats
    const size_t P_FLOATS = (size_t)KS * NROWS * 64 / 2;   // bf16 partials
    const size_t BASE_FLOATS = 40960 + 262144 + P_FLOATS + 524288 + 524288;
    const size_t NEED_PRE_BYTES = (ABF_FLOATS + BASE_FLOATS) * 4ULL;  // ~156.4MB (known good)
    const bool pre = ws_size >= NEED_PRE_BYTES;

    float* base = ws + (pre ? ABF_FLOATS : 0);
    float* wsW  = base;                       // fold area: 40960 floats
    float* St_f = wsW + 40960;                // S^T bf16 [64][8192] (shared)
    float* P_f  = St_f + 262144;              // partials bf16: KS*8192*64
    float* gA   = P_f + P_FLOATS;             // [8192,64]
    float* h4   = gA + 524288;                // [8192,64]
    float* g2   = gA;                         // alias: gA dead after med_chain

    u16* Abf = (u16*)ws;
    u16* St  = (u16*)St_f;
    u16* P   = (u16*)P_f;
    const float* WA = wsW + 0;
    const float* bA = wsW + 8192;
    const float* cA = wsW + 8256;
    const float* WB = wsW + 8320;
    const float* bB = wsW + 9344;
    const float* cB = wsW + 9360;

    fold1<<<18, 256, 0, stream>>>(W1, b1, Wg1, W2, b2, Wg2, wsW);
    fold2<<<10, 256, 0, stream>>>(Wm1, bm1, bg1, W3, b3, bg2, wsW);

    // pass 1 (fused converter): sA^T = (x @ WA + bA)^T ; gA = A@sA + cA
    gemm_rows<128, 64, 0, 0, 1><<<256, 256, 0, stream>>>(x, WA, bA, St);
    if (pre) agg_mfma<64, 1, KS><<<dim3(128, KS), 256, 0, stream>>>(Abf, adj, dis, St, P);
    else     agg_mfma<64, 2, KS><<<dim3(128, KS), 256, 0, stream>>>(nullptr, adj, dis, St, P);
    reduce_add<64, KS><<<256, 256, 0, stream>>>(P, cA, nullptr, gA);

    // fused med chain: gA -> h4 (global) + s2^T (St, bf16)
    med_chain<<<512, 256, 0, stream>>>(gA, Wm2, bm2, Wm3, bm3, Wm4, bm4, Wgh, h4, St);

    // pass 2: g2 = A@s2 + bgh + h4
    if (pre) agg_mfma<64, 0, KS><<<dim3(128, KS), 256, 0, stream>>>(Abf, nullptr, nullptr, St, P);
    else     agg_mfma<64, 2, KS><<<dim3(128, KS), 256, 0, stream>>>(nullptr, adj, dis, St, P);
    reduce_add<64, KS><<<256, 256, 0, stream>>>(P, bgh, h4, g2);

    // pass 3: sB^T = (relu(g2) @ WB + bB)^T ; out = A@sB + cB
    gemm_rows<64, 16, 1, 0, 1><<<256, 256, 0, stream>>>(g2, WB, bB, St);
    if (pre) agg_mfma<16, 0, KS><<<dim3(128, KS), 256, 0, stream>>>(Abf, nullptr, nullptr, St, P);
    else     agg_mfma<16, 2, KS><<<dim3(128, KS), 256, 0, stream>>>(nullptr, adj, dis, St, P);
    reduce_add<16, KS><<<64, 256, 0, stream>>>(P, cB, nullptr, out);
}

// Round 9
// 312.826 us; speedup vs baseline: 1.4222x; 1.0422x over previous
//
#include <hip/hip_runtime.h>
#include <hip/hip_bf16.h>

#define NROWS 8192
typedef unsigned short u16;
typedef short bf16x8 __attribute__((ext_vector_type(8)));
typedef short bf16x4 __attribute__((ext_vector_type(4)));
typedef float f32x4 __attribute__((ext_vector_type(4)));

__device__ __forceinline__ u16 f2b(float f) {   // fp32 -> bf16 RNE (finite data)
    unsigned u = __float_as_uint(f);
    unsigned r = (u + 0x7fffu + ((u >> 16) & 1u)) >> 16;
    return (u16)r;
}
__device__ __forceinline__ float b2f(u16 v) {
    return __uint_as_float(((unsigned)v) << 16);
}

template<int MODE> __device__ __forceinline__ float actf(float v) {
    if constexpr (MODE == 1) return fmaxf(v, 0.f);
    else if constexpr (MODE == 2) return v > 0.f ? v : 0.2f * v;
    else return v;
}

// ---------------------------------------------------------------------------
// Weight folds, parallelized. ws layout (floats):
//   WA[128*64]@0  bA[64]@8192  cA[64]@8256  WB[64*16]@8320  bB[16]@9344
//   cB[16]@9360  T2[64*32]@9376  v1[128]@11424  v2[32]@11552  T1[128*128]@16384
// ---------------------------------------------------------------------------
__global__ __launch_bounds__(256) void fold1(
    const float* __restrict__ W1, const float* __restrict__ b1,
    const float* __restrict__ Wg1,
    const float* __restrict__ W2, const float* __restrict__ b2,
    const float* __restrict__ Wg2, float* __restrict__ ws) {
    float* T2 = ws + 9376;
    float* v1 = ws + 11424;
    float* v2 = ws + 11552;
    float* T1 = ws + 16384;
    const int tid = threadIdx.x, b = blockIdx.x;
    if (b < 16) {                       // T1 = W1 @ Wg1
        int i = b * 8 + (tid >> 5), j4 = (tid & 31) << 2;
        float4 acc = {0, 0, 0, 0};
        for (int k = 0; k < 128; ++k) {
            float a = W1[i * 128 + k];
            float4 g = *(const float4*)&Wg1[k * 128 + j4];
            acc.x += a * g.x; acc.y += a * g.y; acc.z += a * g.z; acc.w += a * g.w;
        }
        *(float4*)&T1[i * 128 + j4] = acc;
    } else if (b == 16) {
        if (tid < 128) {
            float s = 0;
            for (int k = 0; k < 128; ++k) s += b1[k] * Wg1[k * 128 + tid];
            v1[tid] = s;
        } else if (tid < 160) {
            int j = tid - 128;
            float s = 0;
            for (int k = 0; k < 32; ++k) s += b2[k] * Wg2[k * 32 + j];
            v2[j] = s;
        }
    } else {                            // T2 = W2 @ Wg2
        for (int o4 = tid; o4 < 64 * 8; o4 += 256) {
            int i = o4 >> 3, j4 = (o4 & 7) << 2;
            float4 acc = {0, 0, 0, 0};
            for (int k = 0; k < 32; ++k) {
                float a = W2[i * 32 + k];
                float4 g = *(const float4*)&Wg2[k * 32 + j4];
                acc.x += a * g.x; acc.y += a * g.y; acc.z += a * g.z; acc.w += a * g.w;
            }
            *(float4*)&T2[i * 32 + j4] = acc;
        }
    }
}

__global__ __launch_bounds__(256) void fold2(
    const float* __restrict__ Wm1, const float* __restrict__ bm1,
    const float* __restrict__ bg1,
    const float* __restrict__ W3, const float* __restrict__ b3,
    const float* __restrict__ bg2, float* __restrict__ ws) {
    float* WA = ws + 0;
    float* bA = ws + 8192;
    float* cA = ws + 8256;
    float* WB = ws + 8320;
    float* bB = ws + 9344;
    float* cB = ws + 9360;
    const float* T2 = ws + 9376;
    const float* v1 = ws + 11424;
    const float* v2 = ws + 11552;
    const float* T1 = ws + 16384;
    const int tid = threadIdx.x, b = blockIdx.x;
    if (b < 8) {                        // WA = T1 @ Wm1
        int i = b * 16 + (tid >> 4), j4 = (tid & 15) << 2;
        float4 acc = {0, 0, 0, 0};
        for (int k = 0; k < 128; ++k) {
            float a = T1[i * 128 + k];
            float4 g = *(const float4*)&Wm1[k * 64 + j4];
            acc.x += a * g.x; acc.y += a * g.y; acc.z += a * g.z; acc.w += a * g.w;
        }
        *(float4*)&WA[i * 64 + j4] = acc;
    } else if (b == 8) {
        if (tid < 64) {
            float s = 0, c = 0;
            for (int k = 0; k < 128; ++k) {
                s += v1[k] * Wm1[k * 64 + tid];
                c += bg1[k] * Wm1[k * 64 + tid];
            }
            bA[tid] = s; cA[tid] = c + bm1[tid];
        } else if (tid < 80) {
            int j = tid - 64;
            float s = 0, c = 0;
            for (int k = 0; k < 32; ++k) {
                s += v2[k] * W3[k * 16 + j];
                c += bg2[k] * W3[k * 16 + j];
            }
            bB[j] = s; cB[j] = c + b3[j];
        }
    } else {                            // WB = T2 @ W3
        int i = tid >> 2, j4 = (tid & 3) << 2;
        float4 acc = {0, 0, 0, 0};
        for (int k = 0; k < 32; ++k) {
            float a = T2[i * 32 + k];
            float4 g = *(const float4*)&W3[k * 16 + j4];
            acc.x += a * g.x; acc.y += a * g.y; acc.z += a * g.z; acc.w += a * g.w;
        }
        *(float4*)&WB[i * 16 + j4] = acc;
    }
}

// ---------------------------------------------------------------------------
// Small row GEMM: out = AOUT( AIN(in)[N,K] @ W[K,M] + bias )
// OUTT=0: fp32 row-major [N,M].  OUTT=1: bf16 TRANSPOSED [M][NROWS] (S^T).
// ---------------------------------------------------------------------------
template<int K, int M, int AIN, int AOUT, int OUTT>
__global__ __launch_bounds__(256) void gemm_rows(
    const float* __restrict__ in, const float* __restrict__ W,
    const float* __restrict__ bias, void* __restrict__ outv) {
    constexpr int RB = 32;
    constexpr int TNs = (M >= 64) ? 4 : 2;
    constexpr int TXs = M / TNs;
    constexpr int TYs = 256 / TXs;
    constexpr int TMs = RB / TYs;
    static_assert(TMs >= 1 && TMs * TYs == RB, "bad cfg");
    __shared__ float in_t[K][RB + 4];
    __shared__ float w_s[K * M];
    __shared__ float bias_s[M];
    const int tid = threadIdx.x;
    const int b0 = blockIdx.x * RB;
    constexpr int K4 = K / 4;
    for (int g = tid; g < RB * K4; g += 256) {
        int r = g / K4, c4 = g % K4;
        float4 v = *(const float4*)&in[(size_t)(b0 + r) * K + c4 * 4];
        v.x = actf<AIN>(v.x); v.y = actf<AIN>(v.y);
        v.z = actf<AIN>(v.z); v.w = actf<AIN>(v.w);
        in_t[c4 * 4 + 0][r] = v.x;
        in_t[c4 * 4 + 1][r] = v.y;
        in_t[c4 * 4 + 2][r] = v.z;
        in_t[c4 * 4 + 3][r] = v.w;
    }
    for (int g = tid; g < K * M / 4; g += 256)
        ((float4*)w_s)[g] = ((const float4*)W)[g];
    if (tid < M) bias_s[tid] = bias ? bias[tid] : 0.f;
    __syncthreads();

    const int tx = tid % TXs, ty = tid / TXs;
    const int c0 = tx * TNs, r0 = ty * TMs;
    float acc[TMs][TNs] = {};
    for (int k = 0; k < K; ++k) {
        float a[TMs];
#pragma unroll
        for (int m = 0; m < TMs; ++m) a[m] = in_t[k][r0 + m];
        float w[TNs];
#pragma unroll
        for (int n = 0; n < TNs; ++n) w[n] = w_s[k * M + c0 + n];
#pragma unroll
        for (int m = 0; m < TMs; ++m)
#pragma unroll
            for (int n = 0; n < TNs; ++n) acc[m][n] += a[m] * w[n];
    }
#pragma unroll
    for (int m = 0; m < TMs; ++m) {
        float vres[TNs];
#pragma unroll
        for (int n = 0; n < TNs; ++n) vres[n] = actf<AOUT>(acc[m][n] + bias_s[c0 + n]);
        if constexpr (OUTT == 0) {
            float* op = &((float*)outv)[(size_t)(b0 + r0 + m) * M + c0];
            if constexpr (TNs == 4) { float4 o4 = {vres[0], vres[1], vres[2], vres[3]}; *(float4*)op = o4; }
            else                    { float2 o2 = {vres[0], vres[1]}; *(float2*)op = o2; }
        } else {
            u16* ot = (u16*)outv;
#pragma unroll
            for (int n = 0; n < TNs; ++n)
                ot[(size_t)(c0 + n) * NROWS + (b0 + r0 + m)] = f2b(vres[n]);
        }
    }
}

// ---------------------------------------------------------------------------
// Fused med chain, 16 rows/block, 512 blocks. Weights read from global
// (L1-resident broadcast); row panels in LDS (~17KB).
// ---------------------------------------------------------------------------
template<int K, int M, int AOUT, int OMODE>  // OMODE 0: panel; 1: panel+global; 2: St only
__device__ __forceinline__ void layer_step(
    const float (*pin)[17], const float* __restrict__ w,
    const float* __restrict__ bias,
    float (*pout)[17], float* __restrict__ gout, u16* __restrict__ stout,
    int b0, int tid) {
    constexpr int TXs = M / 4;
    constexpr int TYs = 256 / TXs;
    constexpr int TMs = 16 / TYs;
    static_assert(TMs >= 1, "cfg");
    const int tx = tid % TXs, ty = tid / TXs;
    const int c0 = tx * 4, r0 = ty * TMs;
    float acc[TMs][4] = {};
    for (int k = 0; k < K; ++k) {
        float4 wv = *(const float4*)&w[k * M + c0];
#pragma unroll
        for (int m = 0; m < TMs; ++m) {
            float a = pin[k][r0 + m];
            acc[m][0] += a * wv.x; acc[m][1] += a * wv.y;
            acc[m][2] += a * wv.z; acc[m][3] += a * wv.w;
        }
    }
#pragma unroll
    for (int m = 0; m < TMs; ++m) {
        float v[4];
#pragma unroll
        for (int n = 0; n < 4; ++n) {
            float bv = bias ? bias[c0 + n] : 0.f;
            v[n] = actf<AOUT>(acc[m][n] + bv);
        }
        if constexpr (OMODE != 2) {
#pragma unroll
            for (int n = 0; n < 4; ++n) pout[c0 + n][r0 + m] = v[n];
        }
        if constexpr (OMODE == 1) {
            float4 o = {v[0], v[1], v[2], v[3]};
            *(float4*)&gout[(size_t)(b0 + r0 + m) * M + c0] = o;
        }
        if constexpr (OMODE == 2) {
#pragma unroll
            for (int n = 0; n < 4; ++n)
                stout[(size_t)(c0 + n) * NROWS + (b0 + r0 + m)] = f2b(v[n]);
        }
    }
}

__global__ __launch_bounds__(256) void med_chain(
    const float* __restrict__ gA,
    const float* __restrict__ Wm2, const float* __restrict__ bm2,
    const float* __restrict__ Wm3, const float* __restrict__ bm3,
    const float* __restrict__ Wm4, const float* __restrict__ bm4,
    const float* __restrict__ Wgh,
    float* __restrict__ h4, u16* __restrict__ St) {
    __shared__ __align__(16) float P0[64][17];
    __shared__ __align__(16) float P1[128][17];
    __shared__ __align__(16) float P2[64][17];
    const int tid = threadIdx.x;
    const int b0 = blockIdx.x * 16;

    {
        int r = tid >> 4, c4 = tid & 15;
        float4 v = *(const float4*)&gA[(size_t)(b0 + r) * 64 + c4 * 4];
        P0[c4 * 4 + 0][r] = actf<2>(v.x);
        P0[c4 * 4 + 1][r] = actf<2>(v.y);
        P0[c4 * 4 + 2][r] = actf<2>(v.z);
        P0[c4 * 4 + 3][r] = actf<2>(v.w);
    }
    __syncthreads();
    layer_step<64, 128, 2, 0>(P0, Wm2, bm2, P1, nullptr, nullptr, b0, tid);
    __syncthreads();
    layer_step<128, 64, 2, 0>(P1, Wm3, bm3, P2, nullptr, nullptr, b0, tid);
    __syncthreads();
    layer_step<64, 64, 1, 1>(P2, Wm4, bm4, P0, h4, nullptr, b0, tid);
    __syncthreads();
    layer_step<64, 64, 0, 2>(P0, Wgh, nullptr, nullptr, nullptr, St, b0, tid);
}

// ---------------------------------------------------------------------------
// LDS-staged MFMA aggregation with 2-phase register prefetch (T3-minimal):
// issue chunk t+1's global loads right after the barrier, BEFORE MFMA on
// chunk t — the next iteration's barrier drain then lands after a full MFMA
// phase of flight time.  Coalesced global -> regs -> XOR-swizzled LDS ->
// ds_read_b128 fragments.  MODE 0: A from Abf (L3-warm).  MODE 1: A =
// bf16(adj*dis) on the fly (NT reads) + write-back Abf.  MODE 2: no write.
// ---------------------------------------------------------------------------
#define LOAD_A(KC) \
    if constexpr (MODE == 0) { \
        _Pragma("unroll") for (int r = 0; r < AR8; ++r) { \
            int e8 = r * 256 + tid; \
            rA[r] = *(const bf16x8*)(Abf + (size_t)(i0 + (e8 >> 4)) * NROWS + (KC) + (e8 & 15) * 8); \
        } \
    } else { \
        _Pragma("unroll") for (int r = 0; r < AR4; ++r) { \
            int e4 = r * 256 + tid; \
            size_t g = (size_t)(i0 + (e4 >> 5)) * NROWS + (KC) + (e4 & 31) * 4; \
            rAa[r] = __builtin_nontemporal_load((const f32x4*)(adj + g)); \
            rAd[r] = __builtin_nontemporal_load((const f32x4*)(dis + g)); \
        } \
    }

#define LOAD_B(KC) \
    _Pragma("unroll") for (int r = 0; r < BR8; ++r) { \
        int e8 = r * 256 + tid; \
        rB[r] = *(const bf16x8*)(St + (size_t)(e8 >> 4) * NROWS + (KC) + (e8 & 15) * 8); \
    }

#define STORE_A(KC) \
    if constexpr (MODE == 0) { \
        _Pragma("unroll") for (int r = 0; r < AR8; ++r) { \
            int e8 = r * 256 + tid; int row = e8 >> 4; int col = (e8 & 15) * 8; \
            int bo = ((row * BK + col) * 2) ^ ((row & 7) << 4); \
            *(bf16x8*)((char*)As + bo) = rA[r]; \
        } \
    } else { \
        _Pragma("unroll") for (int r = 0; r < AR4; ++r) { \
            int e4 = r * 256 + tid; int row = e4 >> 5; int col = (e4 & 31) * 4; \
            bf16x4 v; \
            _Pragma("unroll") for (int j = 0; j < 4; ++j) v[j] = (short)f2b(rAa[r][j] * rAd[r][j]); \
            if constexpr (MODE == 1) \
                *(bf16x4*)(Abf + (size_t)(i0 + row) * NROWS + (KC) + col) = v; \
            int bo = ((row * BK + col) * 2) ^ ((row & 7) << 4); \
            *(bf16x4*)((char*)As + bo) = v; \
        } \
    }

#define STORE_B() \
    _Pragma("unroll") for (int r = 0; r < BR8; ++r) { \
        int e8 = r * 256 + tid; int c = e8 >> 4; int col = (e8 & 15) * 8; \
        int bo = ((c * BK + col) * 2) ^ ((c & 7) << 4); \
        *(bf16x8*)((char*)Bs + bo) = rB[r]; \
    }

template<int F, int MODE, int KS>
__global__ __launch_bounds__(256) void agg_mfma(
    u16* __restrict__ Abf, const float* __restrict__ adj,
    const float* __restrict__ dis, const u16* __restrict__ St,
    u16* __restrict__ Pout) {
    constexpr int CT = F / 16;
    constexpr int BK = 128;
    constexpr int KCH = NROWS / KS;
    constexpr int NCH = KCH / BK;
    constexpr int AR8 = (64 * BK) / (256 * 8);   // 4
    constexpr int AR4 = (64 * BK) / (256 * 4);   // 8
    constexpr int BR8 = (F * BK) / (256 * 8);    // 4 (F=64) / 1 (F=16)
    __shared__ __align__(16) u16 As[64 * BK];    // 16KB
    __shared__ __align__(16) u16 Bs[F * BK];     // 16KB / 4KB
    const int tid  = threadIdx.x;
    const int lane = tid & 63;
    const int wid  = tid >> 6;
    const int i0   = blockIdx.x * 64;
    const int ky   = blockIdx.y;
    const int l15  = lane & 15;
    const int kb   = (lane >> 4) * 8;
    const int k0   = ky * KCH;
    f32x4 acc[CT] = {};
    bf16x8 rA[AR8];
    f32x4 rAa[AR4], rAd[AR4];
    bf16x8 rB[BR8];

    LOAD_A(k0)
    LOAD_B(k0)
    for (int ch = 0; ch < NCH; ++ch) {
        const int kc = k0 + ch * BK;
        __syncthreads();              // prev MFMA done with LDS (+ vmcnt drain)
        STORE_A(kc)
        STORE_B()
        __syncthreads();
        if (ch + 1 < NCH) {           // prefetch next chunk BEFORE compute
            LOAD_A(kc + BK)
            LOAD_B(kc + BK)
        }
#pragma unroll
        for (int ks = 0; ks < BK; ks += 32) {
            const int arow = wid * 16 + l15;
            int ao = ((arow * BK + ks + kb) * 2) ^ ((arow & 7) << 4);
            bf16x8 af = *(const bf16x8*)((const char*)As + ao);
#pragma unroll
            for (int ct = 0; ct < CT; ++ct) {
                int bcol = ct * 16 + l15;
                int bo = ((bcol * BK + ks + kb) * 2) ^ ((bcol & 7) << 4);
                bf16x8 bf = *(const bf16x8*)((const char*)Bs + bo);
                acc[ct] = __builtin_amdgcn_mfma_f32_16x16x32_bf16(af, bf, acc[ct], 0, 0, 0);
            }
        }
    }
    // C/D layout: col = lane&15, row = (lane>>4)*4 + i   [m89-verified]
    u16* P = Pout + (size_t)ky * ((size_t)NROWS * F);
    const int rb = i0 + wid * 16 + (lane >> 4) * 4;
#pragma unroll
    for (int ct = 0; ct < CT; ++ct)
#pragma unroll
        for (int i = 0; i < 4; ++i)
            P[(size_t)(rb + i) * F + ct * 16 + l15] = f2b(acc[ct][i]);
}
#undef LOAD_A
#undef LOAD_B
#undef STORE_A
#undef STORE_B

// ---------------------------------------------------------------------------
// out = sum_{ky} b2f(P[ky]) + bias[col] (+ res)   (thread = 8 consecutive)
// ---------------------------------------------------------------------------
template<int F, int KS>
__global__ __launch_bounds__(256) void reduce_add(
    const u16* __restrict__ P, const float* __restrict__ bias,
    const float* __restrict__ res, float* __restrict__ out) {
    constexpr int TOT8 = NROWS * F / 8;
    int i8 = blockIdx.x * 256 + threadIdx.x;
    if (i8 >= TOT8) return;
    constexpr size_t STR = (size_t)NROWS * F;
    float s[8] = {};
#pragma unroll
    for (int k = 0; k < KS; ++k) {
        bf16x8 v = *(const bf16x8*)(P + (size_t)k * STR + (size_t)i8 * 8);
#pragma unroll
        for (int j = 0; j < 8; ++j) s[j] += b2f((u16)v[j]);
    }
    const int c0 = (i8 * 8) % F;
#pragma unroll
    for (int j = 0; j < 8; ++j) s[j] += bias[c0 + j];
    if (res) {
        const float4* r4 = (const float4*)(res + (size_t)i8 * 8);
        float4 ra = r4[0], rb = r4[1];
        s[0] += ra.x; s[1] += ra.y; s[2] += ra.z; s[3] += ra.w;
        s[4] += rb.x; s[5] += rb.y; s[6] += rb.z; s[7] += rb.w;
    }
    float4* o4 = (float4*)(out + (size_t)i8 * 8);
    float4 oa = {s[0], s[1], s[2], s[3]}, ob = {s[4], s[5], s[6], s[7]};
    o4[0] = oa; o4[1] = ob;
}

extern "C" void kernel_launch(void* const* d_in, const int* in_sizes, int n_in,
                              void* d_out, int out_size, void* d_ws, size_t ws_size,
                              hipStream_t stream) {
    const float* x   = (const float*)d_in[0];
    const float* adj = (const float*)d_in[1];
    const float* dis = (const float*)d_in[2];
    const float* W1  = (const float*)d_in[3];
    const float* b1  = (const float*)d_in[4];
    const float* Wg1 = (const float*)d_in[5];
    const float* bg1 = (const float*)d_in[6];
    const float* Wm1 = (const float*)d_in[7];
    const float* bm1 = (const float*)d_in[8];
    const float* Wm2 = (const float*)d_in[9];
    const float* bm2 = (const float*)d_in[10];
    const float* Wm3 = (const float*)d_in[11];
    const float* bm3 = (const float*)d_in[12];
    const float* Wm4 = (const float*)d_in[13];
    const float* bm4 = (const float*)d_in[14];
    const float* Wgh = (const float*)d_in[15];
    const float* bgh = (const float*)d_in[16];
    const float* W2  = (const float*)d_in[17];
    const float* b2  = (const float*)d_in[18];
    const float* Wg2 = (const float*)d_in[19];
    const float* bg2 = (const float*)d_in[20];
    const float* W3  = (const float*)d_in[21];
    const float* b3  = (const float*)d_in[22];
    float* ws  = (float*)d_ws;
    float* out = (float*)d_out;

    constexpr int KS = 8;
    const size_t ABF_FLOATS = (size_t)NROWS * NROWS / 2;   // 128MB as floats
    const size_t P_FLOATS = (size_t)KS * NROWS * 64 / 2;   // bf16 partials (8MB)
    const size_t BASE_FLOATS = 40960 + 262144 + P_FLOATS + 524288 + 524288;
    const size_t NEED_PRE_BYTES = (ABF_FLOATS + BASE_FLOATS) * 4ULL;  // ~148MB
    const bool pre = ws_size >= NEED_PRE_BYTES;

    float* base = ws + (pre ? ABF_FLOATS : 0);
    float* wsW  = base;                       // fold area: 40960 floats
    float* St_f = wsW + 40960;                // S^T bf16 [64][8192] (shared)
    float* P_f  = St_f + 262144;              // partials bf16: KS*8192*64
    float* gA   = P_f + P_FLOATS;             // [8192,64]
    float* h4   = gA + 524288;                // [8192,64]
    float* g2   = gA;                         // alias: gA dead after med_chain

    u16* Abf = (u16*)ws;
    u16* St  = (u16*)St_f;
    u16* P   = (u16*)P_f;
    const float* WA = wsW + 0;
    const float* bA = wsW + 8192;
    const float* cA = wsW + 8256;
    const float* WB = wsW + 8320;
    const float* bB = wsW + 9344;
    const float* cB = wsW + 9360;

    fold1<<<18, 256, 0, stream>>>(W1, b1, Wg1, W2, b2, Wg2, wsW);
    fold2<<<10, 256, 0, stream>>>(Wm1, bm1, bg1, W3, b3, bg2, wsW);

    // pass 1 (fused converter): sA^T = (x @ WA + bA)^T ; gA = A@sA + cA
    gemm_rows<128, 64, 0, 0, 1><<<256, 256, 0, stream>>>(x, WA, bA, St);
    if (pre) agg_mfma<64, 1, KS><<<dim3(128, KS), 256, 0, stream>>>(Abf, adj, dis, St, P);
    else     agg_mfma<64, 2, KS><<<dim3(128, KS), 256, 0, stream>>>(nullptr, adj, dis, St, P);
    reduce_add<64, KS><<<256, 256, 0, stream>>>(P, cA, nullptr, gA);

    // fused med chain: gA -> h4 (global) + s2^T (St, bf16)
    med_chain<<<512, 256, 0, stream>>>(gA, Wm2, bm2, Wm3, bm3, Wm4, bm4, Wgh, h4, St);

    // pass 2: g2 = A@s2 + bgh + h4
    if (pre) agg_mfma<64, 0, KS><<<dim3(128, KS), 256, 0, stream>>>(Abf, nullptr, nullptr, St, P);
    else     agg_mfma<64, 2, KS><<<dim3(128, KS), 256, 0, stream>>>(nullptr, adj, dis, St, P);
    reduce_add<64, KS><<<256, 256, 0, stream>>>(P, bgh, h4, g2);

    // pass 3: sB^T = (relu(g2) @ WB + bB)^T ; out = A@sB + cB
    gemm_rows<64, 16, 1, 0, 1><<<256, 256, 0, stream>>>(g2, WB, bB, St);
    if (pre) agg_mfma<16, 0, KS><<<dim3(128, KS), 256, 0, stream>>>(Abf, nullptr, nullptr, St, P);
    else     agg_mfma<16, 2, KS><<<dim3(128, KS), 256, 0, stream>>>(nullptr, adj, dis, St, P);
    reduce_add<16, KS><<<64, 256, 0, stream>>>(P, cB, nullptr, out);
}